// Round 13
// baseline (79.699 us; speedup 1.0000x reference)
//
#include <hip/hip_runtime.h>

#define NCH 16          // feature channels F
#define TLEN 2048       // time length T
#define NTHREADS 256
#define PAD 20          // xWin row stride (floats): 16B-aligned f4 sub-writes

typedef float f4 __attribute__((ext_vector_type(4)));

// One block per batch element. 4 waves; wave w owns positions [512w, 512w+512).
// Phase A: branch-free coalesced stream (R12 static 3-way accumulator
// partition at wave-local tile boundaries (11, 22) / (11, 21) for wave 3)
// PLUS in-stream window capture: the 13 pooling-window x-values are written
// to xWin directly from the stream registers at 7 STATIC unroll positions
// (tiles {0,10,11,20,21,22,31}), with loop-invariant per-wave addresses
// row = A_k + lq and lane predicates lq in [lo_k, hi_k]. This removes the
// 27 MB window re-read entirely — traffic is now the irreducible 256 MiB.
// (R4 did captures with RUNTIME per-iteration conditionals -> scratch spill;
// static predicated writes avoid that. Watch WRITE_SIZE for the signature.)
// Batch remap: co-resident blocks on a CU get contiguous batches.
__global__ __launch_bounds__(NTHREADS, 4) void filternet_kernel(
    const float* __restrict__ x,
    const float* __restrict__ wa1, const float* __restrict__ wa2,
    const float* __restrict__ wa3, const float* __restrict__ wa4,
    const float* __restrict__ wa5, const float* __restrict__ wa6,
    const float* __restrict__ wb1, const float* __restrict__ wb2,
    const float* __restrict__ wb3, const float* __restrict__ wb4,
    const float* __restrict__ wb5, const float* __restrict__ wb6,
    const float* __restrict__ wfc, float* __restrict__ out, int nb)
{
    __shared__ float xWin[13 * 16][PAD];   // window x values -> in-place prefixes
    __shared__ float sWinBase[13][16];     // wave-local prefix at tile boundary
    __shared__ float blkSum[4][16];        // per-512-position block sums
    __shared__ float waL[6][NCH][6];
    __shared__ float wbL[6][6];
    __shared__ float wfcL[108];
    __shared__ float faL[6][12];
    __shared__ float partial[6];

    const int tid = threadIdx.x;
    int b;
    if ((gridDim.x & 255) == 0) {
        const int chunk = gridDim.x >> 8;
        b = (blockIdx.x & 255) * chunk + (blockIdx.x >> 8);
    } else {
        b = blockIdx.x;
    }
    if (b >= nb) return;
    const float* __restrict__ xb = x + (size_t)b * (TLEN * NCH);

    const int l  = tid & 63;      // lane
    const int w  = tid >> 6;      // wave = position block
    const int g  = l & 3;         // channel group (channels 4g..4g+3)
    const int lq = l >> 2;        // position residue within 16-tile

    // ---- weights -> LDS (consumed in phases D/E; the barrier covers it)
    if (tid < 96) {
        const int k0 = tid >> 4, c = tid & 15, K = k0 + 1;
        const float* wp = (k0 == 0) ? wa1 : (k0 == 1) ? wa2 : (k0 == 2) ? wa3
                        : (k0 == 3) ? wa4 : (k0 == 4) ? wa5 : wa6;
        for (int j = 0; j < 6; ++j)
            waL[k0][c][j] = (j < K) ? wp[c * K + j] : 0.0f;
    } else if (tid < 102) {
        const int k0 = tid - 96, K = k0 + 1;
        const float* wp = (k0 == 0) ? wb1 : (k0 == 1) ? wb2 : (k0 == 2) ? wb3
                        : (k0 == 3) ? wb4 : (k0 == 4) ? wb5 : wb6;
        for (int j = 0; j < 6; ++j)
            wbL[k0][j] = (j < K) ? wp[j] : 0.0f;
    } else if (tid >= 128 && tid < 236) {
        wfcL[tid - 128] = wfc[tid - 128];
    }

    // ---- per-wave window overshoots (loop-invariant; all verified by table)
    const int ov0 = (w == 0) ? 0 : (w + 2);          // window 3w   @ q=0/32
    const int ov1 = (w < 2) ? (7 + w) : (8 + w);     // window 3w+1 @ q=11
    const int ov2 = (w == 3) ? 1 : (13 + w);         // window 3w+2 @ q=22 (w3:21)
    const int ov3 = 3 + w;                           // window 3w+3 @ q=32

    // capture points: row = A + lq, enabled iff lq in [lo, hi]
    const int A0  = 48 * w + ov0;                    // u=0  (tile q of win 3w)
    const int A10 = (3 * w + 1) * 16 - (16 - ov1);   // u=10 (tile q-1, win 3w+1)
    const int A11 = (3 * w + 1) * 16 + ov1;          // u=11 (tile q,   win 3w+1)
    const int A20 = 161;                             // u=20 (w=3: tile 20, win 11)
    const int A21 = (w == 3) ? 177 : ((3 * w + 2) * 16 - (16 - ov2)); // u=21
    const int A22 = (3 * w + 2) * 16 + ov2;          // u=22 (w<=2: tile 22)
    const int A31 = (3 * w + 3) * 16 - (16 - ov3);   // u=31 (tile 31, win 3w+3)

    const bool e0  = lq <= 15 - ov0;
    const bool e10 = lq >= 16 - ov1;
    const bool e11 = lq <= 15 - ov1;
    const bool e20 = (w == 3) && (lq == 15);
    const bool e21 = (w == 3) ? (lq <= 14) : (lq >= 16 - ov2);
    const bool e22 = (w != 3) && (lq <= 15 - ov2);
    const bool e31 = lq >= 16 - ov3;

    // precomputed LDS destinations (clamped so disabled lanes stay in-bounds)
#define WROW(A) (((A) + lq) > 207 ? 207 : ((A) + lq))
    f4* p0  = reinterpret_cast<f4*>(&xWin[WROW(A0)][g * 4]);
    f4* p10 = reinterpret_cast<f4*>(&xWin[WROW(A10)][g * 4]);
    f4* p11 = reinterpret_cast<f4*>(&xWin[WROW(A11)][g * 4]);
    f4* p20 = reinterpret_cast<f4*>(&xWin[WROW(A20)][g * 4]);
    f4* p21 = reinterpret_cast<f4*>(&xWin[WROW(A21)][g * 4]);
    f4* p22 = reinterpret_cast<f4*>(&xWin[WROW(A22)][g * 4]);
    f4* p31 = reinterpret_cast<f4*>(&xWin[WROW(A31)][g * 4]);
#undef WROW

    // ---- phase A: branch-free stream + static captures
    f4 a0v = {0.f, 0.f, 0.f, 0.f};
    f4 a1v = a0v, a2v = a0v, aT = a0v;
    const f4* x4 = reinterpret_cast<const f4*>(xb) + ((size_t)w * 2048 + l);
#pragma unroll
    for (int u = 0; u < 8; ++u) {                    // tiles 0..7 -> a0
        f4 v = x4[64 * u];
        if (u == 0 && e0) *p0 = v;
        a0v += v;
    }
#pragma unroll
    for (int u = 8; u < 16; ++u) {                   // 8..10 -> a0 | 11..15 -> a1
        f4 v = x4[64 * u];
        if (u == 10 && e10) *p10 = v;
        if (u == 11 && e11) *p11 = v;
        if (u < 11) a0v += v; else a1v += v;
    }
#pragma unroll
    for (int u = 16; u < 24; ++u) {                  // 16..20 -> a1 | 21 -> aT | 22,23 -> a2
        f4 v = x4[64 * u];
        if (u == 20 && e20) *p20 = v;
        if (u == 21 && e21) *p21 = v;
        if (u == 22 && e22) *p22 = v;
        if (u < 21) a1v += v; else if (u == 21) aT += v; else a2v += v;
    }
#pragma unroll
    for (int u = 24; u < 32; ++u) {                  // tiles 24..31 -> a2
        f4 v = x4[64 * u];
        if (u == 31 && e31) *p31 = v;
        a2v += v;
    }

    if (w == 3) a2v += aT; else a1v += aT;   // wave 3 boundary is 21, others 22
    f4 a01 = a0v + a1v;                      // prefix at local tile 22 (21 for w3)
    f4 tot = a01 + a2v;                      // full wave sum

    // ---- cross-lane reduce (sum the 16 lanes sharing channel group g)
#pragma unroll
    for (int m = 4; m <= 32; m <<= 1) {
#pragma unroll
        for (int e = 0; e < 4; ++e) {
            a0v[e] += __shfl_xor(a0v[e], m, 64);
            a01[e] += __shfl_xor(a01[e], m, 64);
            tot[e] += __shfl_xor(tot[e], m, 64);
        }
    }
    if (l < 4) {
        *reinterpret_cast<f4*>(&sWinBase[3 * w + 1][l * 4]) = a0v;  // prefix @11
        *reinterpret_cast<f4*>(&sWinBase[3 * w + 2][l * 4]) = a01;  // prefix @22/21
        *reinterpret_cast<f4*>(&sWinBase[3 * w + 3][l * 4]) = tot;  // prefix @32
        *reinterpret_cast<f4*>(&blkSum[w][l * 4]) = tot;
        if (w == 0)
            *reinterpret_cast<f4*>(&sWinBase[0][l * 4]) = (f4){0.f, 0.f, 0.f, 0.f};
    }
    __syncthreads();

    // ---- phase C: exact prefixes, in place over xWin (pure LDS)
    if (tid < 13 * 16) {
        const int ci = tid >> 4, c = tid & 15;
        const int cb = (ci == 0) ? 0 : (ci * 2043) / 12 - 1;
        const int wb = cb >> 9;
        const int r  = cb - (wb << 9);
        const int qc = (r + 15) >> 4;        // matches the static boundaries
        const int ov = (qc << 4) - r;        // 0..15 overshoot into window
        float run = sWinBase[ci][c];
        for (int wp = 0; wp < wb; ++wp) run += blkSum[wp][c];
        for (int o = 0; o < ov; ++o) run -= xWin[ci * 16 + o][c];
        // run == P[cb][c]; walk window, replacing values with prefixes
#pragma unroll
        for (int off = 0; off < 16; ++off) {
            const int p = cb + off;
            const float v = xWin[ci * 16 + off][c];
            xWin[ci * 16 + off][c] = run;
            if (p < TLEN) run += v;          // rows with p >= TLEN never consumed
        }
    }
    __syncthreads();

    // ---- phase D: 72 pooled stage-a values
    // pooled_sum[k][i] = sum_j sum_c wa_k[c,j]*(P[e+j][c]-P[s+j][c])
    if (tid < 72) {
        const int k0 = tid / 12, i = tid % 12, K = k0 + 1;
        const int L = TLEN - k0;
        const int s = (i * L) / 12;
        const int e = ((i + 1) * L + 11) / 12;   // ceil((i+1)L/12)
        const int n = e - s;
        const int cbs = (i == 0) ? 0 : (i * 2043) / 12 - 1;
        const int cbe = ((i + 1) * 2043) / 12 - 1;
        const int rs = i * 16 + (s - cbs);
        const int re = (i + 1) * 16 + (e - cbe);
        float acc2 = 0.0f;
        for (int j = 0; j < K; ++j) {
#pragma unroll
            for (int c = 0; c < NCH; ++c)
                acc2 += waL[k0][c][j] * (xWin[re + j][c] - xWin[rs + j][c]);
        }
        float v = acc2 / (float)n;
        faL[k0][i] = (v >= 0.0f) ? v : 0.1f * v;
    }
    __syncthreads();

    // ---- phase E: stage-b conv(dil=2) + pool(lb->6) + leaky + FC partials
    if (tid < 6) {
        const int k0 = tid, K = k0 + 1;
        const int lb = 12 - 2 * k0;
        float fbv[12];
        for (int lo = 0; lo < lb; ++lo) {
            float a = 0.0f;
            for (int j = 0; j < K; ++j) a += wbL[k0][j] * faL[k0][lo + 2 * j];
            fbv[lo] = a;
        }
        float part = 0.0f;
        for (int i2 = 0; i2 < 12; ++i2)
            part += faL[k0][i2] * wfcL[k0 * 18 + i2];
        for (int i6 = 0; i6 < 6; ++i6) {
            const int s6 = (i6 * lb) / 6;
            const int e6 = ((i6 + 1) * lb + 5) / 6;
            float v = 0.0f;
            for (int lo = s6; lo < e6; ++lo) v += fbv[lo];
            v /= (float)(e6 - s6);
            v = (v >= 0.0f) ? v : 0.1f * v;
            part += v * wfcL[k0 * 18 + 12 + i6];
        }
        partial[k0] = part;
    }
    __syncthreads();

    if (tid == 0) {
        out[b] = partial[0] + partial[1] + partial[2] +
                 partial[3] + partial[4] + partial[5];
    }
}

extern "C" void kernel_launch(void* const* d_in, const int* in_sizes, int n_in,
                              void* d_out, int out_size, void* d_ws, size_t ws_size,
                              hipStream_t stream) {
    // Robust input assignment by element count:
    //   x: B*2048*16, wa_k: 16*k (16..96), wb_k: k (1..6), wfc: 108
    const float* x = nullptr;
    const float* wa[6] = {nullptr};
    const float* wb[6] = {nullptr};
    const float* wfc = nullptr;
    int nb = 0;
    for (int i = 0; i < n_in; ++i) {
        const int sz = in_sizes[i];
        const float* p = (const float*)d_in[i];
        if (sz >= TLEN * NCH) { x = p; nb = sz / (TLEN * NCH); }
        else if (sz == 108)   { wfc = p; }
        else if (sz % NCH == 0 && sz >= NCH && sz <= 6 * NCH) { wa[sz / NCH - 1] = p; }
        else if (sz >= 1 && sz <= 6) { wb[sz - 1] = p; }
    }

    float* outp = (float*)d_out;
    dim3 grid(nb), block(NTHREADS);
    hipLaunchKernelGGL(filternet_kernel, grid, block, 0, stream,
                       x, wa[0], wa[1], wa[2], wa[3], wa[4], wa[5],
                       wb[0], wb[1], wb[2], wb[3], wb[4], wb[5],
                       wfc, outp, nb);
}

// Round 14
// 68.392 us; speedup vs baseline: 1.1653x; 1.1653x over previous
//
#include <hip/hip_runtime.h>

#define NCH 16          // feature channels F
#define TLEN 2048       // time length T
#define NTHREADS 256
#define PAD 20          // xWin row stride (floats): 16B-aligned float4 sub-writes

// One block per batch element. 4 waves; wave w owns positions [512w, 512w+512).
// Phase A: coalesced stream (lane l reads float4 x4[2048w + l + 64*it]; 1KiB
// contiguous per wave-instruction), plain loop with unroll 8 (~8 loads in
// flight per wave; ~83 VGPR, no spill at the (256,4) cap). Wave-uniform prefix
// snapshots at window tile boundaries via scalar branches. Window x-values
// re-read by 208 threads, pre-issued before the main loop (L3-served, ~free).
// Batch remap: co-resident blocks on a CU (bid, bid+256, ...) get CONTIGUOUS
// batches -> each CU streams a dense ~1MB window (DRAM row/bank locality).
// FINAL STATE (R14): best of 10 structural variants (68.4 us, ~3.9 TB/s
// pure-read = 25% above the chip's measured copy read-stream rate). Known
// traps, do not revisit: full unroll / named-buffer pipelines spill to
// scratch (R4/R9: 168-245 MB HBM writes); NT loads regress (R11); 2-kernel
// split regresses (R7); in-stream window capture regresses (R13).
__global__ __launch_bounds__(NTHREADS, 4) void filternet_kernel(
    const float* __restrict__ x,
    const float* __restrict__ wa1, const float* __restrict__ wa2,
    const float* __restrict__ wa3, const float* __restrict__ wa4,
    const float* __restrict__ wa5, const float* __restrict__ wa6,
    const float* __restrict__ wb1, const float* __restrict__ wb2,
    const float* __restrict__ wb3, const float* __restrict__ wb4,
    const float* __restrict__ wb5, const float* __restrict__ wb6,
    const float* __restrict__ wfc, float* __restrict__ out, int nb)
{
    __shared__ float xWin[13 * 16][PAD];   // window x values -> in-place prefixes
    __shared__ float sWinBase[13][16];     // P[tile boundary >= window base]
    __shared__ float blkSum[4][16];        // per-512-position block sums
    __shared__ float waL[6][NCH][6];
    __shared__ float wbL[6][6];
    __shared__ float wfcL[108];
    __shared__ float faL[6][12];
    __shared__ float partial[6];

    const int tid = threadIdx.x;
    // CU-contiguous batch remap (blocks bid, bid+256, ... are co-resident on
    // one CU under 8-XCD round-robin dispatch; give them adjacent batches).
    int b;
    if ((gridDim.x & 255) == 0) {
        const int chunk = gridDim.x >> 8;          // batches per CU-slot
        b = (blockIdx.x & 255) * chunk + (blockIdx.x >> 8);
    } else {
        b = blockIdx.x;
    }
    if (b >= nb) return;
    const float* __restrict__ xb = x + (size_t)b * (TLEN * NCH);

    const int l  = tid & 63;      // lane
    const int w  = tid >> 6;      // wave = position block

    // ---- pre-issue window re-reads (fill xWin later; latency hides under loop)
    float4 wv0, wv1, wv2, wv3;
    if (tid < 13 * 16) {
        const int ci = tid >> 4, off = tid & 15;
        const int cb = (ci == 0) ? 0 : (ci * 2043) / 12 - 1;
        const int p = cb + off;
        if (p < TLEN) {
            const float4* xr = reinterpret_cast<const float4*>(xb) + (size_t)p * 4;
            wv0 = xr[0]; wv1 = xr[1]; wv2 = xr[2]; wv3 = xr[3];
        } else {
            wv0 = wv1 = wv2 = wv3 = make_float4(0.f, 0.f, 0.f, 0.f);
        }
    }

    // ---- weights -> LDS (consumed in phases D/E; the barrier covers it)
    if (tid < 96) {
        const int k0 = tid >> 4, c = tid & 15, K = k0 + 1;
        const float* wp = (k0 == 0) ? wa1 : (k0 == 1) ? wa2 : (k0 == 2) ? wa3
                        : (k0 == 3) ? wa4 : (k0 == 4) ? wa5 : wa6;
        for (int j = 0; j < 6; ++j)
            waL[k0][c][j] = (j < K) ? wp[c * K + j] : 0.0f;
    } else if (tid < 102) {
        const int k0 = tid - 96, K = k0 + 1;
        const float* wp = (k0 == 0) ? wb1 : (k0 == 1) ? wb2 : (k0 == 2) ? wb3
                        : (k0 == 3) ? wb4 : (k0 == 4) ? wb5 : wb6;
        for (int j = 0; j < 6; ++j)
            wbL[k0][j] = (j < K) ? wp[j] : 0.0f;
    } else if (tid >= 128 && tid < 236) {
        wfcL[tid - 128] = wfc[tid - 128];
    }

    // ---- per-wave snapshot slots: windows ci = 3w+s (s=0..3) may start in
    // this wave's range. q = snapshot iteration (tile boundary at/above base),
    // -1 if base not in range. Wave-uniform -> force to SGPR (scalar branches).
    int qv0, qv1, qv2, qv3;
    {
        int qt[4];
#pragma unroll
        for (int s = 0; s < 4; ++s) {
            const int ci = 3 * w + s;
            const int cb = (ci == 0) ? 0 : (ci * 2043) / 12 - 1;
            const int r  = cb - (w << 9);
            qt[s] = (r >= 0 && r <= 512) ? ((r + 15) >> 4) : -1;
        }
        qv0 = __builtin_amdgcn_readfirstlane(qt[0]);
        qv1 = __builtin_amdgcn_readfirstlane(qt[1]);
        qv2 = __builtin_amdgcn_readfirstlane(qt[2]);
        qv3 = __builtin_amdgcn_readfirstlane(qt[3]);
    }

    // ---- phase A: pure coalesced stream + scalar-branch snapshots
    float4 acc = make_float4(0.f, 0.f, 0.f, 0.f);
    float4 sn0 = acc, sn1 = acc, sn2 = acc, sn3 = acc;
    const float4* x4 = reinterpret_cast<const float4*>(xb) + ((size_t)w * 2048 + l);
#pragma unroll 8
    for (int it = 0; it < 32; ++it) {
        // snapshot BEFORE adding tile it: acc = prefix over [512w, 512w+16*it)
        if (it == qv0) sn0 = acc;
        if (it == qv1) sn1 = acc;
        if (it == qv2) sn2 = acc;
        if (it == qv3) sn3 = acc;
        float4 v = x4[64 * it];
        acc.x += v.x; acc.y += v.y; acc.z += v.z; acc.w += v.w;
    }
    if (qv0 == 32) sn0 = acc;
    if (qv1 == 32) sn1 = acc;
    if (qv2 == 32) sn2 = acc;
    if (qv3 == 32) sn3 = acc;

    // ---- cross-lane reduce (sum the 16 lanes sharing channel group g = l&3)
    {
        float4 t = acc;
#pragma unroll
        for (int m = 4; m <= 32; m <<= 1) {
            t.x += __shfl_xor(t.x, m, 64); t.y += __shfl_xor(t.y, m, 64);
            t.z += __shfl_xor(t.z, m, 64); t.w += __shfl_xor(t.w, m, 64);
        }
        if (l < 4) *reinterpret_cast<float4*>(&blkSum[w][l * 4]) = t;
    }
#pragma unroll
    for (int s = 0; s < 4; ++s) {
        const int q = (s == 0) ? qv0 : (s == 1) ? qv1 : (s == 2) ? qv2 : qv3;
        if (q >= 0) {
            float4 t = (s == 0) ? sn0 : (s == 1) ? sn1 : (s == 2) ? sn2 : sn3;
#pragma unroll
            for (int m = 4; m <= 32; m <<= 1) {
                t.x += __shfl_xor(t.x, m, 64); t.y += __shfl_xor(t.y, m, 64);
                t.z += __shfl_xor(t.z, m, 64); t.w += __shfl_xor(t.w, m, 64);
            }
            if (l < 4) *reinterpret_cast<float4*>(&sWinBase[3 * w + s][l * 4]) = t;
        }
    }

    // ---- commit pre-issued window values to LDS
    if (tid < 13 * 16) {
        float4* dst = reinterpret_cast<float4*>(&xWin[tid][0]);
        dst[0] = wv0; dst[1] = wv1; dst[2] = wv2; dst[3] = wv3;
    }
    __syncthreads();

    // ---- phase C: exact prefixes, in place over xWin (pure LDS)
    if (tid < 13 * 16) {
        const int ci = tid >> 4, c = tid & 15;
        const int cb = (ci == 0) ? 0 : (ci * 2043) / 12 - 1;
        const int wb = cb >> 9;
        const int r  = cb - (wb << 9);
        const int qc = (r + 15) >> 4;        // <= 32
        const int ov = (qc << 4) - r;        // 0..15 overshoot into window
        float run = sWinBase[ci][c];
        for (int wp = 0; wp < wb; ++wp) run += blkSum[wp][c];
        for (int o = 0; o < ov; ++o) run -= xWin[ci * 16 + o][c];
        // run == P[cb][c]; walk window, replacing values with prefixes
#pragma unroll
        for (int off = 0; off < 16; ++off) {
            const int p = cb + off;
            const float v = xWin[ci * 16 + off][c];
            xWin[ci * 16 + off][c] = run;
            if (p < TLEN) run += v;
        }
    }
    __syncthreads();

    // ---- phase D: 72 pooled stage-a values
    // pooled_sum[k][i] = sum_j sum_c wa_k[c,j]*(P[e+j][c]-P[s+j][c])
    if (tid < 72) {
        const int k0 = tid / 12, i = tid % 12, K = k0 + 1;
        const int L = TLEN - k0;
        const int s = (i * L) / 12;
        const int e = ((i + 1) * L + 11) / 12;   // ceil((i+1)L/12)
        const int n = e - s;
        const int cbs = (i == 0) ? 0 : (i * 2043) / 12 - 1;
        const int cbe = ((i + 1) * 2043) / 12 - 1;
        const int rs = i * 16 + (s - cbs);
        const int re = (i + 1) * 16 + (e - cbe);
        float acc2 = 0.0f;
        for (int j = 0; j < K; ++j) {
#pragma unroll
            for (int c = 0; c < NCH; ++c)
                acc2 += waL[k0][c][j] * (xWin[re + j][c] - xWin[rs + j][c]);
        }
        float v = acc2 / (float)n;
        faL[k0][i] = (v >= 0.0f) ? v : 0.1f * v;
    }
    __syncthreads();

    // ---- phase E: stage-b conv(dil=2) + pool(lb->6) + leaky + FC partials
    if (tid < 6) {
        const int k0 = tid, K = k0 + 1;
        const int lb = 12 - 2 * k0;
        float fbv[12];
        for (int lo = 0; lo < lb; ++lo) {
            float a = 0.0f;
            for (int j = 0; j < K; ++j) a += wbL[k0][j] * faL[k0][lo + 2 * j];
            fbv[lo] = a;
        }
        float part = 0.0f;
        for (int i2 = 0; i2 < 12; ++i2)
            part += faL[k0][i2] * wfcL[k0 * 18 + i2];
        for (int i6 = 0; i6 < 6; ++i6) {
            const int s6 = (i6 * lb) / 6;
            const int e6 = ((i6 + 1) * lb + 5) / 6;
            float v = 0.0f;
            for (int lo = s6; lo < e6; ++lo) v += fbv[lo];
            v /= (float)(e6 - s6);
            v = (v >= 0.0f) ? v : 0.1f * v;
            part += v * wfcL[k0 * 18 + 12 + i6];
        }
        partial[k0] = part;
    }
    __syncthreads();

    if (tid == 0) {
        out[b] = partial[0] + partial[1] + partial[2] +
                 partial[3] + partial[4] + partial[5];
    }
}

extern "C" void kernel_launch(void* const* d_in, const int* in_sizes, int n_in,
                              void* d_out, int out_size, void* d_ws, size_t ws_size,
                              hipStream_t stream) {
    // Robust input assignment by element count:
    //   x: B*2048*16, wa_k: 16*k (16..96), wb_k: k (1..6), wfc: 108
    const float* x = nullptr;
    const float* wa[6] = {nullptr};
    const float* wb[6] = {nullptr};
    const float* wfc = nullptr;
    int nb = 0;
    for (int i = 0; i < n_in; ++i) {
        const int sz = in_sizes[i];
        const float* p = (const float*)d_in[i];
        if (sz >= TLEN * NCH) { x = p; nb = sz / (TLEN * NCH); }
        else if (sz == 108)   { wfc = p; }
        else if (sz % NCH == 0 && sz >= NCH && sz <= 6 * NCH) { wa[sz / NCH - 1] = p; }
        else if (sz >= 1 && sz <= 6) { wb[sz - 1] = p; }
    }

    float* outp = (float*)d_out;
    dim3 grid(nb), block(NTHREADS);
    hipLaunchKernelGGL(filternet_kernel, grid, block, 0, stream,
                       x, wa[0], wa[1], wa[2], wa[3], wa[4], wa[5],
                       wb[0], wb[1], wb[2], wb[3], wb[4], wb[5],
                       wfc, outp, nb);
}